// Round 5
// baseline (591.929 us; speedup 1.0000x reference)
//
#include <hip/hip_runtime.h>
#include <hip/hip_bf16.h>

#define NNODES 20000
#define NEDGES 640000
#define NB 50
#define NF 128

typedef unsigned int uint_t;
typedef unsigned short ushort_t;

typedef __bf16 bf16x8 __attribute__((ext_vector_type(8)));
typedef float f32x4 __attribute__((ext_vector_type(4)));

// fp32 -> bf16 bits (round to nearest even), returned in low 16 bits
__device__ __forceinline__ uint_t f2bf(float f) {
    uint_t u = __float_as_uint(f);
    return (u + 0x7fffu + ((u >> 16) & 1u)) >> 16;
}

// fast shifted softplus: hardware v_exp_f32 / v_log_f32
__device__ __forceinline__ float ssp_f(float x) {
    float t = __expf(-fabsf(x));
    return fmaxf(x, 0.0f) + __logf(1.0f + t) - 0.6931471805599453f;
}

// ---------------- zero the aggregation buffer (capture-safe) ----------------
__global__ __launch_bounds__(256) void k_zero(float4* __restrict__ p) {
    int i = blockIdx.x * 256 + threadIdx.x;   // 2500*256 = 640000 float4 = 2.56M floats exactly
    p[i] = make_float4(0.f, 0.f, 0.f, 0.f);
}

// ---------------- node GEMM: Y = X @ W  (MFMA, 64-row tile) ----------------
__global__ __launch_bounds__(256) void k_node1(const float* __restrict__ X,
                                               const float* __restrict__ W,
                                               float* __restrict__ Y, int nrows)
{
    __shared__ alignas(16) ushort_t sx[64 * 136];
    const int tid  = threadIdx.x;
    const int wv   = tid >> 6, lane = tid & 63;
    const int col  = lane & 15, quad = lane >> 4;

    bf16x8 wf[2][4];
    #pragma unroll
    for (int nt = 0; nt < 2; ++nt) {
        int n = wv * 32 + nt * 16 + col;
        #pragma unroll
        for (int kc = 0; kc < 4; ++kc)
            #pragma unroll
            for (int j = 0; j < 8; ++j)
                wf[nt][kc][j] = (__bf16)W[(kc * 32 + quad * 8 + j) * NF + n];
    }

    const int rbase = blockIdx.x * 64;
    for (int i = tid; i < 64 * 64; i += 256) {
        int r = i >> 6, c = i & 63;
        int gr = rbase + r;
        float2 v = (gr < nrows) ? *reinterpret_cast<const float2*>(&X[(size_t)gr * NF + 2 * c])
                                : make_float2(0.f, 0.f);
        reinterpret_cast<uint_t*>(sx)[r * 68 + c] = f2bf(v.x) | (f2bf(v.y) << 16);
    }
    __syncthreads();

    f32x4 acc[4][2] = {};
    #pragma unroll
    for (int kc = 0; kc < 4; ++kc) {
        bf16x8 af[4];
        #pragma unroll
        for (int mt = 0; mt < 4; ++mt)
            af[mt] = *reinterpret_cast<const bf16x8*>(&sx[(mt * 16 + col) * 136 + kc * 32 + quad * 8]);
        #pragma unroll
        for (int mt = 0; mt < 4; ++mt)
            #pragma unroll
            for (int nt = 0; nt < 2; ++nt)
                acc[mt][nt] = __builtin_amdgcn_mfma_f32_16x16x32_bf16(af[mt], wf[nt][kc], acc[mt][nt], 0, 0, 0);
    }
    #pragma unroll
    for (int mt = 0; mt < 4; ++mt)
        #pragma unroll
        for (int nt = 0; nt < 2; ++nt)
            #pragma unroll
            for (int r = 0; r < 4; ++r) {
                int row = rbase + mt * 16 + quad * 4 + r;
                if (row < nrows) Y[(size_t)row * NF + wv * 32 + nt * 16 + col] = acc[mt][nt][r];
            }
}

// ---------------- fused tail: out = ssp(X @ W1 + b1) @ W2 + b2 ----------------
__global__ __launch_bounds__(256) void k_tail(const float* __restrict__ X,
                                              const float* __restrict__ W1, const float* __restrict__ B1,
                                              const float* __restrict__ W2, const float* __restrict__ B2,
                                              float* __restrict__ Y, int nrows)
{
    __shared__ alignas(16) ushort_t sx[64 * 136];
    __shared__ alignas(16) ushort_t st[64 * 136];
    const int tid  = threadIdx.x;
    const int wv   = tid >> 6, lane = tid & 63;
    const int col  = lane & 15, quad = lane >> 4;

    bf16x8 wf1[2][4], wf2[2][4];
    float rb1[2], rb2[2];
    #pragma unroll
    for (int nt = 0; nt < 2; ++nt) {
        int n = wv * 32 + nt * 16 + col;
        rb1[nt] = B1[n]; rb2[nt] = B2[n];
        #pragma unroll
        for (int kc = 0; kc < 4; ++kc)
            #pragma unroll
            for (int j = 0; j < 8; ++j) {
                int k = kc * 32 + quad * 8 + j;
                wf1[nt][kc][j] = (__bf16)W1[k * NF + n];
                wf2[nt][kc][j] = (__bf16)W2[k * NF + n];
            }
    }

    const int rbase = blockIdx.x * 64;
    for (int i = tid; i < 64 * 64; i += 256) {
        int r = i >> 6, c = i & 63;
        int gr = rbase + r;
        float2 v = (gr < nrows) ? *reinterpret_cast<const float2*>(&X[(size_t)gr * NF + 2 * c])
                                : make_float2(0.f, 0.f);
        reinterpret_cast<uint_t*>(sx)[r * 68 + c] = f2bf(v.x) | (f2bf(v.y) << 16);
    }
    __syncthreads();

    f32x4 acc[4][2];
    #pragma unroll
    for (int mt = 0; mt < 4; ++mt)
        #pragma unroll
        for (int nt = 0; nt < 2; ++nt)
            acc[mt][nt] = f32x4{rb1[nt], rb1[nt], rb1[nt], rb1[nt]};
    #pragma unroll
    for (int kc = 0; kc < 4; ++kc) {
        bf16x8 af[4];
        #pragma unroll
        for (int mt = 0; mt < 4; ++mt)
            af[mt] = *reinterpret_cast<const bf16x8*>(&sx[(mt * 16 + col) * 136 + kc * 32 + quad * 8]);
        #pragma unroll
        for (int mt = 0; mt < 4; ++mt)
            #pragma unroll
            for (int nt = 0; nt < 2; ++nt)
                acc[mt][nt] = __builtin_amdgcn_mfma_f32_16x16x32_bf16(af[mt], wf1[nt][kc], acc[mt][nt], 0, 0, 0);
    }
    #pragma unroll
    for (int mt = 0; mt < 4; ++mt)
        #pragma unroll
        for (int nt = 0; nt < 2; ++nt)
            #pragma unroll
            for (int r = 0; r < 4; ++r)
                st[(mt * 16 + quad * 4 + r) * 136 + wv * 32 + nt * 16 + col] =
                    (ushort_t)f2bf(ssp_f(acc[mt][nt][r]));
    __syncthreads();

    f32x4 acc2[4][2];
    #pragma unroll
    for (int mt = 0; mt < 4; ++mt)
        #pragma unroll
        for (int nt = 0; nt < 2; ++nt)
            acc2[mt][nt] = f32x4{rb2[nt], rb2[nt], rb2[nt], rb2[nt]};
    #pragma unroll
    for (int kc = 0; kc < 4; ++kc) {
        bf16x8 af[4];
        #pragma unroll
        for (int mt = 0; mt < 4; ++mt)
            af[mt] = *reinterpret_cast<const bf16x8*>(&st[(mt * 16 + col) * 136 + kc * 32 + quad * 8]);
        #pragma unroll
        for (int mt = 0; mt < 4; ++mt)
            #pragma unroll
            for (int nt = 0; nt < 2; ++nt)
                acc2[mt][nt] = __builtin_amdgcn_mfma_f32_16x16x32_bf16(af[mt], wf2[nt][kc], acc2[mt][nt], 0, 0, 0);
    }
    #pragma unroll
    for (int mt = 0; mt < 4; ++mt)
        #pragma unroll
        for (int nt = 0; nt < 2; ++nt)
            #pragma unroll
            for (int r = 0; r < 4; ++r) {
                int row = rbase + mt * 16 + quad * 4 + r;
                if (row < nrows) Y[(size_t)row * NF + wv * 32 + nt * 16 + col] = acc2[mt][nt][r];
            }
}

// ---------------- fused edge MLP (MFMA) + CFConv gather/scatter ----------------
// Barrier-free after weight staging: 4 waves/block, each wave fully owns
// 16-edge x 128-filter tiles. A-frags built in registers from global; weight
// B-frags pre-swizzled in LDS (lane-contiguous 16B); layer1->layer2 transpose
// via wave-private LDS slice (no __syncthreads).
// Grid MUST be 2000 blocks: 2000 * 4 waves * 5 iters * 16 edges = 640000.
__global__ __launch_bounds__(256) void k_edge(
    const int* __restrict__ esrc, const int* __restrict__ edst,
    const float* __restrict__ ew, const float* __restrict__ ea,
    const float* __restrict__ w1, const float* __restrict__ b1,
    const float* __restrict__ w2, const float* __restrict__ b2,
    const float* __restrict__ h, float* __restrict__ agg)
{
    __shared__ alignas(16) ushort_t w1f[16 * 64 * 8];   // 16 KB, frag = ntg*2+kc
    __shared__ alignas(16) ushort_t w2f[32 * 64 * 8];   // 32 KB, frag = ntg*4+kc
    __shared__ alignas(16) ushort_t st1[4][16 * 72];    // 9 KB, wave-private 64-filter halves

    const int tid  = threadIdx.x;
    const int wv   = tid >> 6, lane = tid & 63;
    const int col  = lane & 15, quad = lane >> 4;

    // stage weight B-fragments: frag(ntg,kc), lane l holds W[k=kc*32+(l>>4)*8+j][n=ntg*16+(l&15)]
    for (int idx = tid; idx < 16 * 64; idx += 256) {
        int fr = idx >> 6, l = idx & 63;
        int ntg = fr >> 1, kc = fr & 1;
        int n = ntg * 16 + (l & 15), kb = kc * 32 + (l >> 4) * 8;
        ushort_t* d = &w1f[idx * 8];
        #pragma unroll
        for (int j = 0; j < 8; ++j) {
            int k = kb + j;
            d[j] = (ushort_t)((k < NB) ? f2bf(w1[k * NF + n]) : 0u);
        }
    }
    for (int idx = tid; idx < 32 * 64; idx += 256) {
        int fr = idx >> 6, l = idx & 63;
        int ntg = fr >> 2, kc = fr & 3;
        int n = ntg * 16 + (l & 15), kb = kc * 32 + (l >> 4) * 8;
        ushort_t* d = &w2f[idx * 8];
        #pragma unroll
        for (int j = 0; j < 8; ++j)
            d[j] = (ushort_t)f2bf(w2[(kb + j) * NF + n]);
    }
    float rb1[8], rb2[8];
    #pragma unroll
    for (int nt = 0; nt < 8; ++nt) { rb1[nt] = b1[nt * 16 + col]; rb2[nt] = b2[nt * 16 + col]; }
    __syncthreads();   // the only barrier

    ushort_t* myst = st1[wv];

    for (int it = 0; it < 5; ++it) {
        const int ebase = blockIdx.x * 320 + wv * 80 + it * 16;

        // per-lane edge meta: 4 edges quad*4+r (16 lanes broadcast-share each)
        int srcv[4], dstv[4];
        float Cw[4];
        #pragma unroll
        for (int r = 0; r < 4; ++r) {
            int e = ebase + quad * 4 + r;
            srcv[r] = esrc[e];
            dstv[r] = edst[e];
            Cw[r]   = 0.5f * (__cosf(ew[e] * 0.31415926535897931f) + 1.0f);
        }

        // hoisted gathers: latency hides behind the whole MLP
        float hg[8][4];
        #pragma unroll
        for (int nt = 0; nt < 8; ++nt)
            #pragma unroll
            for (int r = 0; r < 4; ++r)
                hg[nt][r] = h[(size_t)srcv[r] * NF + nt * 16 + col];

        // build layer-1 A-frags in registers (lane = edge col)
        const float* erow = ea + (size_t)(ebase + col) * NB;
        bf16x8 af0, af1;
        #pragma unroll
        for (int p = 0; p < 4; ++p) {
            float2 v = *reinterpret_cast<const float2*>(erow + quad * 8 + 2 * p);
            af0[2 * p]     = (__bf16)v.x;
            af0[2 * p + 1] = (__bf16)v.y;
        }
        #pragma unroll
        for (int p = 0; p < 4; ++p) {
            int k = 32 + quad * 8 + 2 * p;
            float2 v = (k + 2 <= NB) ? *reinterpret_cast<const float2*>(erow + k)
                                     : make_float2(0.f, 0.f);
            af1[2 * p]     = (__bf16)v.x;
            af1[2 * p + 1] = (__bf16)v.y;
        }

        f32x4 acc2[8];
        #pragma unroll
        for (int nt = 0; nt < 8; ++nt) acc2[nt] = f32x4{rb2[nt], rb2[nt], rb2[nt], rb2[nt]};

        #pragma unroll
        for (int hf = 0; hf < 2; ++hf) {
            // layer 1 for filters hf*64 .. hf*64+63
            f32x4 acc1[4];
            #pragma unroll
            for (int nt = 0; nt < 4; ++nt) {
                int ntg = hf * 4 + nt;
                acc1[nt] = f32x4{rb1[ntg], rb1[ntg], rb1[ntg], rb1[ntg]};
                bf16x8 bw0 = *reinterpret_cast<const bf16x8*>(&w1f[((ntg * 2 + 0) * 64 + lane) * 8]);
                bf16x8 bw1 = *reinterpret_cast<const bf16x8*>(&w1f[((ntg * 2 + 1) * 64 + lane) * 8]);
                acc1[nt] = __builtin_amdgcn_mfma_f32_16x16x32_bf16(af0, bw0, acc1[nt], 0, 0, 0);
                acc1[nt] = __builtin_amdgcn_mfma_f32_16x16x32_bf16(af1, bw1, acc1[nt], 0, 0, 0);
            }
            // ssp -> wave-private st1 (layer-2 A-layout, row=edge, col=filter-in-half)
            #pragma unroll
            for (int nt = 0; nt < 4; ++nt)
                #pragma unroll
                for (int r = 0; r < 4; ++r)
                    myst[(quad * 4 + r) * 72 + nt * 16 + col] = (ushort_t)f2bf(ssp_f(acc1[nt][r]));
            // layer 2 partial: K-chunks hf*2, hf*2+1
            bf16x8 a20 = *reinterpret_cast<const bf16x8*>(&myst[col * 72 + 0 * 32 + quad * 8]);
            bf16x8 a21 = *reinterpret_cast<const bf16x8*>(&myst[col * 72 + 1 * 32 + quad * 8]);
            #pragma unroll
            for (int nt = 0; nt < 8; ++nt) {
                bf16x8 b20 = *reinterpret_cast<const bf16x8*>(&w2f[((nt * 4 + hf * 2 + 0) * 64 + lane) * 8]);
                bf16x8 b21 = *reinterpret_cast<const bf16x8*>(&w2f[((nt * 4 + hf * 2 + 1) * 64 + lane) * 8]);
                acc2[nt] = __builtin_amdgcn_mfma_f32_16x16x32_bf16(a20, b20, acc2[nt], 0, 0, 0);
                acc2[nt] = __builtin_amdgcn_mfma_f32_16x16x32_bf16(a21, b21, acc2[nt], 0, 0, 0);
            }
        }

        // epilogue: cutoff * gather * scatter (fire-and-forget atomics)
        #pragma unroll
        for (int nt = 0; nt < 8; ++nt)
            #pragma unroll
            for (int r = 0; r < 4; ++r)
                atomicAdd(&agg[(size_t)dstv[r] * NF + nt * 16 + col],
                          acc2[nt][r] * Cw[r] * hg[nt][r]);
    }
}

extern "C" void kernel_launch(void* const* d_in, const int* in_sizes, int n_in,
                              void* d_out, int out_size, void* d_ws, size_t ws_size,
                              hipStream_t stream) {
    const float* x    = (const float*)d_in[0];   // [20000,128] fp32
    const int*   eidx = (const int*)d_in[1];     // [2,640000] int32
    const float* ew   = (const float*)d_in[2];   // [640000]
    const float* ea   = (const float*)d_in[3];   // [640000,50]
    const float* w1   = (const float*)d_in[4];   // [50,128]
    const float* b1   = (const float*)d_in[5];   // [128]
    const float* w2   = (const float*)d_in[6];   // [128,128]
    const float* b2   = (const float*)d_in[7];   // [128]
    const float* l1w  = (const float*)d_in[8];   // [128,128]
    const float* l2w  = (const float*)d_in[9];   // [128,128]
    const float* l2b  = (const float*)d_in[10];  // [128]
    const float* lw   = (const float*)d_in[11];  // [128,128]
    const float* lb   = (const float*)d_in[12];  // [128]
    (void)in_sizes; (void)n_in; (void)out_size; (void)ws_size;

    float* h   = (float*)d_ws;                                    // 10.24 MB
    float* agg = (float*)((char*)d_ws + (size_t)NNODES * NF * 4);  // 10.24 MB

    hipLaunchKernelGGL(k_zero, dim3(2500), dim3(256), 0, stream, (float4*)agg);
    // h = x @ lin1_w  (MFMA)
    hipLaunchKernelGGL(k_node1, dim3(313), dim3(256), 0, stream, x, l1w, h, NNODES);
    // fused edge MLP (MFMA, barrier-free) + CFConv scatter
    hipLaunchKernelGGL(k_edge, dim3(2000), dim3(256), 0, stream,
                       eidx, eidx + NEDGES, ew, ea, w1, b1, w2, b2, h, agg);
    // out = ssp(agg @ lin2_w + lin2_b) @ lin_w + lin_b  (fused MFMA)
    hipLaunchKernelGGL(k_tail, dim3(313), dim3(256), 0, stream,
                       agg, l2w, l2b, lw, lb, (float*)d_out, NNODES);
}